// Round 6
// baseline (653.644 us; speedup 1.0000x reference)
//
#include <hip/hip_runtime.h>
#include <math.h>

#define LEAKY(x) ((x) >= 0.f ? (x) : 0.3f*(x))

// ---- workspace float offsets ----
#define G_OFF   0         // 648     extracted g~ (72x9)
#define IM_OFF  648       // 7776    im (b,ch,81)
#define LAM_OFF 8424      // 32      lambda per batch
#define WB_OFF  8456      // 2592    w branch (b,81)
#define YBR_OFF 11048     // 82944   y branch (b,81,32)
#define X1_OFF  93992     // 663552  conv51 out (b,36,36,16)
#define X2_OFF  757544    // 331776  conv15 out (b,18,18,32)
#define X3_OFF  1089320   // 165888  conv55 out (b,9,9,64)

#define OUT0 106272       // elements in output 0; cs_out follows

// 8-lane butterfly sum via DPP (groups aligned at lane%8==0).
// quad_perm[1,0,3,2]=0xB1, quad_perm[2,3,0,1]=0x4E, row_half_mirror=0x141.
template<int CTRL>
__device__ __forceinline__ float dpp_add(float v) {
    int m = __builtin_amdgcn_update_dpp(0, __float_as_int(v), CTRL, 0xF, 0xF, true);
    return v + __int_as_float(m);
}
__device__ __forceinline__ float red8(float v) {
    v = dpp_add<0xB1>(v);
    v = dpp_add<0x4E>(v);
    v = dpp_add<0x141>(v);
    return v;
}

// ======================= prep =======================
__global__ __launch_bounds__(256) void prep_kernel(
    const float* __restrict__ inp, const float* __restrict__ mat,
    const float* __restrict__ w1_k, const float* __restrict__ w1_b,
    const float* __restrict__ x1_k, const float* __restrict__ x1_b,
    const float* __restrict__ y17_k, const float* __restrict__ y17_b,
    const float* __restrict__ y71_k, const float* __restrict__ y71_b,
    const float* __restrict__ yc_k, const float* __restrict__ yc_b,
    const float* __restrict__ d1_k, const float* __restrict__ d2_k,
    const float* __restrict__ h1_w, const float* __restrict__ h1_b,
    const float* __restrict__ h2_w, const float* __restrict__ h2_b,
    const float* __restrict__ h3_w, const float* __restrict__ h3_b,
    float* __restrict__ ws)
{
    int t = threadIdx.x;
    if (blockIdx.x == 0) {
        // extract separable factor: g[i][a] = mat[i*72, a*9] / sqrt(mat[0,0])
        float rs = rsqrtf(mat[0]);
        for (int u = t; u < 648; u += 256) {
            int i = u / 9, a = u % 9;
            ws[G_OFF + u] = mat[(size_t)(i*72)*81 + a*9] * rs;
        }
        return;
    }
    int b = blockIdx.x - 1;
    __shared__ float sin_[243];
    __shared__ float cm[27];
    __shared__ float cat[5184];
    __shared__ float z1[108];
    __shared__ float z2[24];
    __shared__ float v1[24];
    __shared__ float v2[12];

    const float BN  = 1.0f / sqrtf(1.001f);
    const float BN2 = BN * BN;

    for (int u = t; u < 243; u += 256) sin_[u] = inp[b*243 + u];
    __syncthreads();

    // w branch (t<81), colmax (81..107), d1 conv (128..235)
    if (t < 81) {
        float s = w1_b[0];
        for (int i = 0; i < 3; ++i) s += sin_[t*3+i] * w1_k[i];
        ws[WB_OFF + b*81 + t] = LEAKY(s);
    } else if (t < 108) {
        int u = t - 81;                       // c*3+ch
        float m = 0.f;
        for (int r = 0; r < 9; ++r) m = fmaxf(m, fabsf(sin_[r*27 + u]));
        cm[u] = 0.001f + m;
    }
    if (t >= 128 && t < 236) {
        int u = t - 128;                      // oy*36 + ox*12 + o
        int o = u % 12, ox = (u/12) % 3, oy = u/36;
        float s = 0.f;
        for (int kh = 0; kh < 5; ++kh) {
            int iy = oy*3 - 1 + kh;
            if (iy < 0 || iy > 8) continue;
            for (int kw = 0; kw < 5; ++kw) {
                int ix = ox*3 - 1 + kw;
                if (ix < 0 || ix > 8) continue;
                for (int i = 0; i < 3; ++i)
                    s += sin_[(iy*9+ix)*3 + i] * d1_k[((kh*5+kw)*3 + i)*12 + o];
            }
        }
        z1[u] = LEAKY(BN2 * s);
    }
    __syncthreads();

    // im = leaky(conv1x1(inp / colmax)) ; layout (b,ch,81)
    if (t < 243) {
        int o = t / 81, p = t % 81;
        int c = p % 9;
        float s = x1_b[o];
        for (int i = 0; i < 3; ++i)
            s += (sin_[p*3+i] / cm[c*3+i]) * x1_k[i*3 + o];
        ws[IM_OFF + (b*3 + o)*81 + p] = LEAKY(s);
    }
    __syncthreads();

    // d2 conv: 3x3x12 -> 1x1x24 (kernel rows/cols 1..3 valid)
    if (t < 24) {
        float s = 0.f;
        for (int kh = 1; kh < 4; ++kh)
            for (int kw = 1; kw < 4; ++kw)
                for (int i = 0; i < 12; ++i)
                    s += z1[((kh-1)*3 + (kw-1))*12 + i] * d2_k[((kh*5+kw)*12 + i)*24 + t];
        z2[t] = LEAKY(BN * s);
    }
    __syncthreads();
    if (t < 24) {
        float s = h1_b[t];
        for (int i = 0; i < 24; ++i) s += z2[i] * h1_w[i*24 + t];
        v1[t] = s;
    }
    __syncthreads();
    if (t < 12) {
        float s = h2_b[t];
        for (int i = 0; i < 24; ++i) s += v1[i] * h2_w[i*12 + t];
        v2[t] = s;
    }
    __syncthreads();
    if (t == 0) {
        float s = h3_b[0];
        for (int i = 0; i < 12; ++i) s += v2[i] * h3_w[i];
        ws[LAM_OFF + b] = 0.01f / (1.f + expf(-s));   // 0.1*sigmoid * 0.1
    }

    // y branch: cat = [y1(32) | y2(32)] per position
    for (int u = t; u < 5184; u += 256) {
        int pos = u / 64, i = u % 64;
        int r = pos / 9, c = pos % 9;
        float s;
        if (i < 32) {
            s = y17_b[i];
            for (int kw = 0; kw < 7; ++kw) {
                int cc = c - 3 + kw;
                if (cc < 0 || cc > 8) continue;
                for (int ii = 0; ii < 3; ++ii)
                    s += sin_[(r*9+cc)*3 + ii] * y17_k[(kw*3+ii)*32 + i];
            }
        } else {
            int i2 = i - 32;
            s = y71_b[i2];
            for (int kh = 0; kh < 7; ++kh) {
                int rr = r - 3 + kh;
                if (rr < 0 || rr > 8) continue;
                for (int ii = 0; ii < 3; ++ii)
                    s += sin_[(rr*9+c)*3 + ii] * y71_k[(kh*3+ii)*32 + i2];
            }
        }
        cat[pos*64 + i] = s;
    }
    __syncthreads();
    for (int u = t; u < 2592; u += 256) {
        int pos = u / 32, o = u % 32;
        float s = yc_b[o];
        for (int i = 0; i < 64; ++i) s += cat[pos*64 + i] * yc_k[i*32 + o];
        ws[YBR_OFF + (b*81 + pos)*32 + o] = LEAKY(s);
    }
}

// ======================= FISTA =======================
// One block per (b,ch), 648 threads (10.125 waves). 3 barriers/iter; all
// partial-sum reductions via 8-lane DPP butterflies (no LDS atomics, no
// reduce phases).
//   P1 (648 thr, task (j1=t/9, a1=t%9)): Qtt[j1*12+a1] = dot9(R row a1, Gj)
//   P2 (576 thr, j2=t/8, grp=t%8, rows grp*9..+8): y-update in regs,
//       9 col-partials DPP-reduced over grp-lanes; lane-spread T write.
//   P3 (648 thr, ab=t/8, seg=t%8): dot12(T[a][seg*12..], GTr) DPP-reduced
//       over seg-lanes; lane seg==0 writes R = im - S.
__global__ __launch_bounds__(648, 1) void fista_kernel(
    const float* __restrict__ ws, float* __restrict__ cs_out)
{
    __shared__ float Qtt[864];     // [j][12] (9 used, 3 pad)
    __shared__ float T[648];       // [a][72]
    __shared__ float R[108];       // [a][12] (9 used)

    int t = threadIdx.x;
    int b = blockIdx.x / 3, ch = blockIdx.x % 3;
    const float* g = ws + G_OFF;
    const float* im = ws + IM_OFF + (b*3 + ch)*81;
    float lam = ws[LAM_OFF + b];

    // ---- P1 role ----
    int j1 = t / 9, a1 = t - j1*9;
    float Gj[9];
#pragma unroll
    for (int a = 0; a < 9; ++a) Gj[a] = g[j1*9 + a];

    // ---- P2 role ----
    int j2 = t >> 3, grp = t & 7;           // j2<72 valid only for t<576
    bool act = t < 576;                     // wave-uniform (9 full waves)
    float Gr[81];
    if (act) {
#pragma unroll
        for (int s = 0; s < 9; ++s)
#pragma unroll
            for (int a = 0; a < 9; ++a)
                Gr[s*9 + a] = g[(grp*9 + s)*9 + a];
    }

    // ---- P3 role ----
    int ab = t >> 3, seg = t & 7;           // ab 0..80, seg 0..7
    int a3 = ab / 9, b3 = ab - a3*9;
    float GTr[12];
#pragma unroll
    for (int r = 0; r < 12; ++r)
        GTr[r] = (seg < 6) ? g[(seg*12 + r)*9 + b3] : 0.f;
    float im_s = (seg == 0) ? im[ab] : 0.f;

    // initial R = im
    if (t < 81) R[(t/9)*12 + (t%9)] = im[t];

    float Yv[9], Yl[9];
#pragma unroll
    for (int s = 0; s < 9; ++s) { Yv[s] = 0.f; Yl[s] = 0.f; }
    float tk = 1.f;
    __syncthreads();

    for (int it = 0; it < 100; ++it) {
        // ---- P1: Qtt[j][a] = dot9(R row a, G row j)
        {
            const float4* R4 = (const float4*)(R + a1*12);
            float4 r0 = R4[0], r1 = R4[1], r2 = R4[2];
            Qtt[j1*12 + a1] =
                r0.x*Gj[0] + r0.y*Gj[1] + r0.z*Gj[2] + r0.w*Gj[3]
              + r1.x*Gj[4] + r1.y*Gj[5] + r1.z*Gj[6] + r1.w*Gj[7]
              + r2.x*Gj[8];
        }
        __syncthreads();
        float tn = 0.5f*(1.f + sqrtf(1.f + 4.f*tk*tk));
        float cmom = (tk - 1.f) / tn;
        tk = tn;
        // ---- P2: y-update + DPP column partials
        float u0=0,u1=0,u2=0,u3=0,u4=0,u5=0,u6=0,u7=0,u8=0;
        if (act) {
            const float4* Q4 = (const float4*)(Qtt + j2*12);
            float4 qa = Q4[0], qb = Q4[1], qc = Q4[2];
            float q0=qa.x,q1=qa.y,q2=qa.z,q3=qa.w,
                  q4=qb.x,q5=qb.y,q6=qb.z,q7=qb.w,q8=qc.x;
#pragma unroll
            for (int s = 0; s < 9; ++s) {
                float re = Gr[s*9+0]*q0 + Gr[s*9+1]*q1 + Gr[s*9+2]*q2
                         + Gr[s*9+3]*q3 + Gr[s*9+4]*q4 + Gr[s*9+5]*q5
                         + Gr[s*9+6]*q6 + Gr[s*9+7]*q7 + Gr[s*9+8]*q8;
                float wv = Yv[s] + re;
                float aa = fabsf(wv) - lam;
                float yn = aa > 0.f ? copysignf(aa, wv) : 0.f;
                float yx = yn + cmom*(yn - Yl[s]);
                Yl[s] = yn; Yv[s] = yx;
                u0 += yx*Gr[s*9+0]; u1 += yx*Gr[s*9+1]; u2 += yx*Gr[s*9+2];
                u3 += yx*Gr[s*9+3]; u4 += yx*Gr[s*9+4]; u5 += yx*Gr[s*9+5];
                u6 += yx*Gr[s*9+6]; u7 += yx*Gr[s*9+7]; u8 += yx*Gr[s*9+8];
            }
        }
        if (it == 99) break;
        if (act) {
            u0 = red8(u0); u1 = red8(u1); u2 = red8(u2);
            u3 = red8(u3); u4 = red8(u4); u5 = red8(u5);
            u6 = red8(u6); u7 = red8(u7); u8 = red8(u8);
            // lane grp writes column total for a=grp; lane 0 also a=8
            float tv = grp==0 ? u0 : grp==1 ? u1 : grp==2 ? u2 : grp==3 ? u3
                     : grp==4 ? u4 : grp==5 ? u5 : grp==6 ? u6 : u7;
            T[grp*72 + j2] = tv;
            if (grp == 0) T[8*72 + j2] = u8;
        }
        __syncthreads();
        // ---- P3: S[a][b] via segment dot-12 + DPP reduce; R = im - S
        {
            float part = 0.f;
            if (seg < 6) {
                const float4* T4 = (const float4*)(T + a3*72 + seg*12);
                float4 t0 = T4[0], t1 = T4[1], t2 = T4[2];
                part = t0.x*GTr[0] + t0.y*GTr[1] + t0.z*GTr[2] + t0.w*GTr[3]
                     + t1.x*GTr[4] + t1.y*GTr[5] + t1.z*GTr[6] + t1.w*GTr[7]
                     + t2.x*GTr[8] + t2.y*GTr[9] + t2.z*GTr[10]+ t2.w*GTr[11];
            }
            part = red8(part);
            if (seg == 0) R[a3*12 + b3] = im_s - part;
        }
        __syncthreads();
    }
    if (act) {
#pragma unroll
        for (int s = 0; s < 9; ++s) {
            int i = grp*9 + s;
            cs_out[(size_t)(b*5184 + i*72 + j2)*3 + ch] = Yl[s];
        }
    }
}

// ======================= post convs =======================
__global__ __launch_bounds__(256) void c51_kernel(
    const float* __restrict__ cs, const float* __restrict__ k,
    const float* __restrict__ bias, float* __restrict__ out)
{
    int id = blockIdx.x*256 + threadIdx.x;
    if (id >= 32*36*36*16) return;
    int o = id & 15; int rest = id >> 4;
    int ox = rest % 36; rest /= 36; int oy = rest % 36; int b = rest / 36;
    float s = bias[o];
    int ix = ox*2;
    for (int kh = 0; kh < 5; ++kh) {
        int iy = oy*2 - 1 + kh;
        if (iy < 0 || iy >= 72) continue;
        const float* p = cs + ((size_t)(b*72 + iy)*72 + ix)*3;
        const float* kk = k + kh*48 + o;
        s += p[0]*kk[0] + p[1]*kk[16] + p[2]*kk[32];
    }
    out[id] = s;
}

__global__ __launch_bounds__(256) void c15_kernel(
    const float* __restrict__ x1, const float* __restrict__ k,
    const float* __restrict__ bias, float* __restrict__ out)
{
    int id = blockIdx.x*256 + threadIdx.x;
    if (id >= 32*18*18*32) return;
    int o = id & 31; int rest = id >> 5;
    int ox = rest % 18; rest /= 18; int oy = rest % 18; int b = rest / 18;
    float s = bias[o];
    int iy = oy*2;
    for (int kw = 0; kw < 5; ++kw) {
        int ix = ox*2 - 1 + kw;
        if (ix < 0 || ix >= 36) continue;
        const float* p = x1 + ((size_t)(b*36 + iy)*36 + ix)*16;
        const float* kk = k + kw*512 + o;
        for (int i = 0; i < 16; ++i) s += p[i]*kk[i*32];
    }
    out[id] = s;
}

__global__ __launch_bounds__(256) void c55_kernel(
    const float* __restrict__ x2, const float* __restrict__ k,
    const float* __restrict__ bias, float* __restrict__ out)
{
    int id = blockIdx.x*256 + threadIdx.x;
    if (id >= 32*9*9*64) return;
    int o = id & 63; int rest = id >> 6;
    int ox = rest % 9; rest /= 9; int oy = rest % 9; int b = rest / 9;
    float s = bias[o];
    for (int kh = 0; kh < 5; ++kh) {
        int iy = oy*2 - 1 + kh;
        if (iy < 0 || iy >= 18) continue;
        for (int kw = 0; kw < 5; ++kw) {
            int ix = ox*2 - 1 + kw;
            if (ix < 0 || ix >= 18) continue;
            const float* p = x2 + ((size_t)(b*18 + iy)*18 + ix)*32;
            const float* kk = k + (kh*5+kw)*2048 + o;
            for (int i = 0; i < 32; ++i) s += p[i]*kk[i*64];
        }
    }
    out[id] = s;
}

__global__ __launch_bounds__(256) void out_kernel(
    const float* __restrict__ ws, const float* __restrict__ x2_k,
    const float* __restrict__ x2_b, float* __restrict__ out)
{
    int id = blockIdx.x*256 + threadIdx.x;
    if (id >= OUT0) return;
    int q = id % 41; int rest = id / 41;
    int cc = rest % 9; rest /= 9; int r = rest % 9; int b = rest / 9;
    float val;
    if (q == 0) {
        val = ws[WB_OFF + b*81 + r*9 + cc];
    } else if (q <= 8) {
        int o = q - 1;
        const float* p = ws + X3_OFF + ((size_t)(b*9 + r)*9 + cc)*64;
        float s = x2_b[o];
        for (int i = 0; i < 64; ++i) s += p[i]*x2_k[i*8 + o];
        val = LEAKY(s);
    } else {
        val = ws[YBR_OFF + ((size_t)(b*81 + r*9 + cc))*32 + (q - 9)];
    }
    out[id] = val;
}

// ======================= launch =======================
extern "C" void kernel_launch(void* const* d_in, const int* in_sizes, int n_in,
                              void* d_out, int out_size, void* d_ws, size_t ws_size,
                              hipStream_t stream) {
    const float* inp   = (const float*)d_in[0];
    const float* mat   = (const float*)d_in[1];
    const float* w1_k  = (const float*)d_in[2];
    const float* w1_b  = (const float*)d_in[3];
    const float* x1_k  = (const float*)d_in[4];
    const float* x1_b  = (const float*)d_in[5];
    const float* c51_k = (const float*)d_in[6];
    const float* c51_b = (const float*)d_in[7];
    const float* c15_k = (const float*)d_in[8];
    const float* c15_b = (const float*)d_in[9];
    const float* c55_k = (const float*)d_in[10];
    const float* c55_b = (const float*)d_in[11];
    const float* x2_k  = (const float*)d_in[12];
    const float* x2_b  = (const float*)d_in[13];
    const float* y17_k = (const float*)d_in[14];
    const float* y17_b = (const float*)d_in[15];
    const float* y71_k = (const float*)d_in[16];
    const float* y71_b = (const float*)d_in[17];
    const float* yc_k  = (const float*)d_in[18];
    const float* yc_b  = (const float*)d_in[19];
    const float* d1_k  = (const float*)d_in[20];
    const float* d2_k  = (const float*)d_in[21];
    const float* h1_w  = (const float*)d_in[22];
    const float* h1_b  = (const float*)d_in[23];
    const float* h2_w  = (const float*)d_in[24];
    const float* h2_b  = (const float*)d_in[25];
    const float* h3_w  = (const float*)d_in[26];
    const float* h3_b  = (const float*)d_in[27];

    float* ws  = (float*)d_ws;
    float* out = (float*)d_out;
    float* cs  = out + OUT0;

    hipLaunchKernelGGL(prep_kernel, dim3(33), dim3(256), 0, stream,
        inp, mat, w1_k, w1_b, x1_k, x1_b, y17_k, y17_b, y71_k, y71_b,
        yc_k, yc_b, d1_k, d2_k, h1_w, h1_b, h2_w, h2_b, h3_w, h3_b, ws);
    hipLaunchKernelGGL(fista_kernel, dim3(96), dim3(648), 0, stream, ws, cs);
    hipLaunchKernelGGL(c51_kernel, dim3(2592), dim3(256), 0, stream, cs, c51_k, c51_b, ws + X1_OFF);
    hipLaunchKernelGGL(c15_kernel, dim3(1296), dim3(256), 0, stream, ws + X1_OFF, c15_k, c15_b, ws + X2_OFF);
    hipLaunchKernelGGL(c55_kernel, dim3(648), dim3(256), 0, stream, ws + X2_OFF, c55_k, c55_b, ws + X3_OFF);
    hipLaunchKernelGGL(out_kernel, dim3(416), dim3(256), 0, stream, ws, x2_k, x2_b, out);
}

// Round 7
// 629.995 us; speedup vs baseline: 1.0375x; 1.0375x over previous
//
#include <hip/hip_runtime.h>
#include <math.h>

#define LEAKY(x) ((x) >= 0.f ? (x) : 0.3f*(x))

// ---- workspace float offsets ----
#define G_OFF   0         // 648     extracted g~ (72x9)
#define IM_OFF  648       // 7776    im (b,ch,81)
#define LAM_OFF 8424      // 32      lambda per batch
#define WB_OFF  8456      // 2592    w branch (b,81)
#define YBR_OFF 11048     // 82944   y branch (b,81,32)
#define X1_OFF  93992     // 663552  conv51 out (b,36,36,16)
#define X2_OFF  757544    // 331776  conv15 out (b,18,18,32)
#define X3_OFF  1089320   // 165888  conv55 out (b,9,9,64)

#define OUT0 106272       // elements in output 0; cs_out follows

// 8-lane butterfly sum via DPP (groups aligned at lane%8==0).
// quad_perm[1,0,3,2]=0xB1, quad_perm[2,3,0,1]=0x4E, row_half_mirror=0x141.
template<int CTRL>
__device__ __forceinline__ float dpp_add(float v) {
    int m = __builtin_amdgcn_update_dpp(0, __float_as_int(v), CTRL, 0xF, 0xF, true);
    return v + __int_as_float(m);
}
__device__ __forceinline__ float red8(float v) {
    v = dpp_add<0xB1>(v);
    v = dpp_add<0x4E>(v);
    v = dpp_add<0x141>(v);
    return v;
}

// ======================= prep =======================
__global__ __launch_bounds__(256) void prep_kernel(
    const float* __restrict__ inp, const float* __restrict__ mat,
    const float* __restrict__ w1_k, const float* __restrict__ w1_b,
    const float* __restrict__ x1_k, const float* __restrict__ x1_b,
    const float* __restrict__ y17_k, const float* __restrict__ y17_b,
    const float* __restrict__ y71_k, const float* __restrict__ y71_b,
    const float* __restrict__ yc_k, const float* __restrict__ yc_b,
    const float* __restrict__ d1_k, const float* __restrict__ d2_k,
    const float* __restrict__ h1_w, const float* __restrict__ h1_b,
    const float* __restrict__ h2_w, const float* __restrict__ h2_b,
    const float* __restrict__ h3_w, const float* __restrict__ h3_b,
    float* __restrict__ ws)
{
    int t = threadIdx.x;
    if (blockIdx.x == 0) {
        // extract separable factor: g[i][a] = mat[i*72, a*9] / sqrt(mat[0,0])
        float rs = rsqrtf(mat[0]);
        for (int u = t; u < 648; u += 256) {
            int i = u / 9, a = u % 9;
            ws[G_OFF + u] = mat[(size_t)(i*72)*81 + a*9] * rs;
        }
        return;
    }
    int b = blockIdx.x - 1;
    __shared__ float sin_[243];
    __shared__ float cm[27];
    __shared__ float cat[5184];
    __shared__ float z1[108];
    __shared__ float z2[24];
    __shared__ float v1[24];
    __shared__ float v2[12];

    const float BN  = 1.0f / sqrtf(1.001f);
    const float BN2 = BN * BN;

    for (int u = t; u < 243; u += 256) sin_[u] = inp[b*243 + u];
    __syncthreads();

    // w branch (t<81), colmax (81..107), d1 conv (128..235)
    if (t < 81) {
        float s = w1_b[0];
        for (int i = 0; i < 3; ++i) s += sin_[t*3+i] * w1_k[i];
        ws[WB_OFF + b*81 + t] = LEAKY(s);
    } else if (t < 108) {
        int u = t - 81;                       // c*3+ch
        float m = 0.f;
        for (int r = 0; r < 9; ++r) m = fmaxf(m, fabsf(sin_[r*27 + u]));
        cm[u] = 0.001f + m;
    }
    if (t >= 128 && t < 236) {
        int u = t - 128;                      // oy*36 + ox*12 + o
        int o = u % 12, ox = (u/12) % 3, oy = u/36;
        float s = 0.f;
        for (int kh = 0; kh < 5; ++kh) {
            int iy = oy*3 - 1 + kh;
            if (iy < 0 || iy > 8) continue;
            for (int kw = 0; kw < 5; ++kw) {
                int ix = ox*3 - 1 + kw;
                if (ix < 0 || ix > 8) continue;
                for (int i = 0; i < 3; ++i)
                    s += sin_[(iy*9+ix)*3 + i] * d1_k[((kh*5+kw)*3 + i)*12 + o];
            }
        }
        z1[u] = LEAKY(BN2 * s);
    }
    __syncthreads();

    // im = leaky(conv1x1(inp / colmax)) ; layout (b,ch,81)
    if (t < 243) {
        int o = t / 81, p = t % 81;
        int c = p % 9;
        float s = x1_b[o];
        for (int i = 0; i < 3; ++i)
            s += (sin_[p*3+i] / cm[c*3+i]) * x1_k[i*3 + o];
        ws[IM_OFF + (b*3 + o)*81 + p] = LEAKY(s);
    }
    __syncthreads();

    // d2 conv: 3x3x12 -> 1x1x24 (kernel rows/cols 1..3 valid)
    if (t < 24) {
        float s = 0.f;
        for (int kh = 1; kh < 4; ++kh)
            for (int kw = 1; kw < 4; ++kw)
                for (int i = 0; i < 12; ++i)
                    s += z1[((kh-1)*3 + (kw-1))*12 + i] * d2_k[((kh*5+kw)*12 + i)*24 + t];
        z2[t] = LEAKY(BN * s);
    }
    __syncthreads();
    if (t < 24) {
        float s = h1_b[t];
        for (int i = 0; i < 24; ++i) s += z2[i] * h1_w[i*24 + t];
        v1[t] = s;
    }
    __syncthreads();
    if (t < 12) {
        float s = h2_b[t];
        for (int i = 0; i < 24; ++i) s += v1[i] * h2_w[i*12 + t];
        v2[t] = s;
    }
    __syncthreads();
    if (t == 0) {
        float s = h3_b[0];
        for (int i = 0; i < 12; ++i) s += v2[i] * h3_w[i];
        ws[LAM_OFF + b] = 0.01f / (1.f + expf(-s));   // 0.1*sigmoid * 0.1
    }

    // y branch: cat = [y1(32) | y2(32)] per position
    for (int u = t; u < 5184; u += 256) {
        int pos = u / 64, i = u % 64;
        int r = pos / 9, c = pos % 9;
        float s;
        if (i < 32) {
            s = y17_b[i];
            for (int kw = 0; kw < 7; ++kw) {
                int cc = c - 3 + kw;
                if (cc < 0 || cc > 8) continue;
                for (int ii = 0; ii < 3; ++ii)
                    s += sin_[(r*9+cc)*3 + ii] * y17_k[(kw*3+ii)*32 + i];
            }
        } else {
            int i2 = i - 32;
            s = y71_b[i2];
            for (int kh = 0; kh < 7; ++kh) {
                int rr = r - 3 + kh;
                if (rr < 0 || rr > 8) continue;
                for (int ii = 0; ii < 3; ++ii)
                    s += sin_[(rr*9+c)*3 + ii] * y71_k[(kh*3+ii)*32 + i2];
            }
        }
        cat[pos*64 + i] = s;
    }
    __syncthreads();
    for (int u = t; u < 2592; u += 256) {
        int pos = u / 32, o = u % 32;
        float s = yc_b[o];
        for (int i = 0; i < 64; ++i) s += cat[pos*64 + i] * yc_k[i*32 + o];
        ws[YBR_OFF + (b*81 + pos)*32 + o] = LEAKY(s);
    }
}

// ======================= FISTA =======================
// One block per (b,ch), 704 threads (11 full waves). 3 barriers/iter.
// Residual folded into precomputed Qim (= im.G, iteration-invariant):
//   Q[j][a] = Qim[j][a] - sum_b V[a][b] g[j][b],  V = T.G
// Roles (register budgets kept disjoint to avoid the R6 spill):
//   P1 (t<648, (j1,a1)): Qtt[j][a] from V + Gj[9] regs          (LDS: 4r+1w)
//   P2 (t<576, (j2,grp)): y-update, Gr[81] regs, DPP-8 col sums (LDS: 3r+2w)
//   P3 (t<648, (ab,seg)): V[a][b] via seg-dot12 from LDS GTs + DPP-8
__global__ __launch_bounds__(704, 1) void fista_kernel(
    const float* __restrict__ ws, float* __restrict__ cs_out)
{
    __shared__ float GTs[648];   // [b][72]  G^T rows
    __shared__ float Qim[864];   // [j][12]
    __shared__ float Qtt[864];   // [j][12]
    __shared__ float T[648];     // [a][72]
    __shared__ float V[108];     // [a][12]
    __shared__ float imL[108];   // [a][12]

    int t = threadIdx.x;
    int b = blockIdx.x / 3, ch = blockIdx.x % 3;
    const float* g = ws + G_OFF;
    const float* im = ws + IM_OFF + (b*3 + ch)*81;
    float lam = ws[LAM_OFF + b];

    bool p1 = t < 648;
    int j1 = t / 9, a1 = t - j1*9;
    bool p2 = t < 576;
    int j2 = t >> 3, grp = t & 7;
    int ab = t >> 3, seg = t & 7;          // P3: ab<81 exactly when t<648
    int a3 = ab / 9, b3 = ab - a3*9;

    float Gj[9];
    if (p1) {
#pragma unroll
        for (int a = 0; a < 9; ++a) Gj[a] = g[j1*9 + a];
    }
    float Gr[81];
    if (p2) {
#pragma unroll
        for (int s = 0; s < 9; ++s)
#pragma unroll
            for (int a = 0; a < 9; ++a)
                Gr[s*9 + a] = g[(grp*9 + s)*9 + a];
    }

    // one-time LDS init
    if (p1) GTs[t] = g[(t % 72)*9 + t/72];
    if (t < 108) {
        int a = t / 12, c = t - a*12;
        imL[t] = (c < 9) ? im[a*9 + c] : 0.f;
        V[t] = 0.f;
    }
    __syncthreads();
    if (p1) {
        const float4* I4 = (const float4*)(imL + a1*12);
        float4 r0 = I4[0], r1 = I4[1], r2 = I4[2];
        Qim[j1*12 + a1] =
            r0.x*Gj[0] + r0.y*Gj[1] + r0.z*Gj[2] + r0.w*Gj[3]
          + r1.x*Gj[4] + r1.y*Gj[5] + r1.z*Gj[6] + r1.w*Gj[7]
          + r2.x*Gj[8];
    }
    __syncthreads();

    float Yv[9], Yl[9];
#pragma unroll
    for (int s = 0; s < 9; ++s) { Yv[s] = 0.f; Yl[s] = 0.f; }
    float tk = 1.f;

    for (int it = 0; it < 100; ++it) {
        // ---- P1: Qtt[j][a] = Qim[j][a] - dot9(V row a, Gj)
        if (p1) {
            const float4* V4 = (const float4*)(V + a1*12);
            float4 v0 = V4[0], v1 = V4[1], v2 = V4[2];
            Qtt[j1*12 + a1] = Qim[j1*12 + a1]
                - (v0.x*Gj[0] + v0.y*Gj[1] + v0.z*Gj[2] + v0.w*Gj[3]
                 + v1.x*Gj[4] + v1.y*Gj[5] + v1.z*Gj[6] + v1.w*Gj[7]
                 + v2.x*Gj[8]);
        }
        __syncthreads();
        float tn = 0.5f*(1.f + sqrtf(1.f + 4.f*tk*tk));
        float cmom = (tk - 1.f) / tn;
        tk = tn;
        // ---- P2: y-update + DPP column partials
        float u0=0,u1=0,u2=0,u3=0,u4=0,u5=0,u6=0,u7=0,u8=0;
        if (p2) {
            const float4* Q4 = (const float4*)(Qtt + j2*12);
            float4 qa = Q4[0], qb = Q4[1], qc = Q4[2];
            float q0=qa.x,q1=qa.y,q2=qa.z,q3=qa.w,
                  q4=qb.x,q5=qb.y,q6=qb.z,q7=qb.w,q8=qc.x;
#pragma unroll
            for (int s = 0; s < 9; ++s) {
                float re = Gr[s*9+0]*q0 + Gr[s*9+1]*q1 + Gr[s*9+2]*q2
                         + Gr[s*9+3]*q3 + Gr[s*9+4]*q4 + Gr[s*9+5]*q5
                         + Gr[s*9+6]*q6 + Gr[s*9+7]*q7 + Gr[s*9+8]*q8;
                float wv = Yv[s] + re;
                float aa = fabsf(wv) - lam;
                float yn = aa > 0.f ? copysignf(aa, wv) : 0.f;
                float yx = yn + cmom*(yn - Yl[s]);
                Yl[s] = yn; Yv[s] = yx;
                u0 += yx*Gr[s*9+0]; u1 += yx*Gr[s*9+1]; u2 += yx*Gr[s*9+2];
                u3 += yx*Gr[s*9+3]; u4 += yx*Gr[s*9+4]; u5 += yx*Gr[s*9+5];
                u6 += yx*Gr[s*9+6]; u7 += yx*Gr[s*9+7]; u8 += yx*Gr[s*9+8];
            }
        }
        if (it == 99) break;
        if (p2) {
            u0 = red8(u0); u1 = red8(u1); u2 = red8(u2);
            u3 = red8(u3); u4 = red8(u4); u5 = red8(u5);
            u6 = red8(u6); u7 = red8(u7); u8 = red8(u8);
            float tv = grp==0 ? u0 : grp==1 ? u1 : grp==2 ? u2 : grp==3 ? u3
                     : grp==4 ? u4 : grp==5 ? u5 : grp==6 ? u6 : u7;
            T[grp*72 + j2] = tv;
            if (grp == 0) T[8*72 + j2] = u8;
        }
        __syncthreads();
        // ---- P3: V[a][b] = sum_j T[a][j] GT[b][j] via seg-dot12 + DPP
        if (p1) {
            float part = 0.f;
            if (seg < 6) {
                const float4* T4 = (const float4*)(T + a3*72 + seg*12);
                const float4* G4 = (const float4*)(GTs + b3*72 + seg*12);
                float4 t0 = T4[0], t1 = T4[1], t2 = T4[2];
                float4 g0 = G4[0], g1 = G4[1], g2 = G4[2];
                part = t0.x*g0.x + t0.y*g0.y + t0.z*g0.z + t0.w*g0.w
                     + t1.x*g1.x + t1.y*g1.y + t1.z*g1.z + t1.w*g1.w
                     + t2.x*g2.x + t2.y*g2.y + t2.z*g2.z + t2.w*g2.w;
            }
            part = red8(part);
            if (seg == 0) V[a3*12 + b3] = part;
        }
        __syncthreads();
    }
    if (p2) {
#pragma unroll
        for (int s = 0; s < 9; ++s) {
            int i = grp*9 + s;
            cs_out[(size_t)(b*5184 + i*72 + j2)*3 + ch] = Yl[s];
        }
    }
}

// ======================= post convs =======================
__global__ __launch_bounds__(256) void c51_kernel(
    const float* __restrict__ cs, const float* __restrict__ k,
    const float* __restrict__ bias, float* __restrict__ out)
{
    int id = blockIdx.x*256 + threadIdx.x;
    if (id >= 32*36*36*16) return;
    int o = id & 15; int rest = id >> 4;
    int ox = rest % 36; rest /= 36; int oy = rest % 36; int b = rest / 36;
    float s = bias[o];
    int ix = ox*2;
    for (int kh = 0; kh < 5; ++kh) {
        int iy = oy*2 - 1 + kh;
        if (iy < 0 || iy >= 72) continue;
        const float* p = cs + ((size_t)(b*72 + iy)*72 + ix)*3;
        const float* kk = k + kh*48 + o;
        s += p[0]*kk[0] + p[1]*kk[16] + p[2]*kk[32];
    }
    out[id] = s;
}

__global__ __launch_bounds__(256) void c15_kernel(
    const float* __restrict__ x1, const float* __restrict__ k,
    const float* __restrict__ bias, float* __restrict__ out)
{
    int id = blockIdx.x*256 + threadIdx.x;
    if (id >= 32*18*18*32) return;
    int o = id & 31; int rest = id >> 5;
    int ox = rest % 18; rest /= 18; int oy = rest % 18; int b = rest / 18;
    float s = bias[o];
    int iy = oy*2;
    for (int kw = 0; kw < 5; ++kw) {
        int ix = ox*2 - 1 + kw;
        if (ix < 0 || ix >= 36) continue;
        const float* p = x1 + ((size_t)(b*36 + iy)*36 + ix)*16;
        const float* kk = k + kw*512 + o;
        for (int i = 0; i < 16; ++i) s += p[i]*kk[i*32];
    }
    out[id] = s;
}

__global__ __launch_bounds__(256) void c55_kernel(
    const float* __restrict__ x2, const float* __restrict__ k,
    const float* __restrict__ bias, float* __restrict__ out)
{
    int id = blockIdx.x*256 + threadIdx.x;
    if (id >= 32*9*9*64) return;
    int o = id & 63; int rest = id >> 6;
    int ox = rest % 9; rest /= 9; int oy = rest % 9; int b = rest / 9;
    float s = bias[o];
    for (int kh = 0; kh < 5; ++kh) {
        int iy = oy*2 - 1 + kh;
        if (iy < 0 || iy >= 18) continue;
        for (int kw = 0; kw < 5; ++kw) {
            int ix = ox*2 - 1 + kw;
            if (ix < 0 || ix >= 18) continue;
            const float* p = x2 + ((size_t)(b*18 + iy)*18 + ix)*32;
            const float* kk = k + (kh*5+kw)*2048 + o;
            for (int i = 0; i < 32; ++i) s += p[i]*kk[i*64];
        }
    }
    out[id] = s;
}

__global__ __launch_bounds__(256) void out_kernel(
    const float* __restrict__ ws, const float* __restrict__ x2_k,
    const float* __restrict__ x2_b, float* __restrict__ out)
{
    int id = blockIdx.x*256 + threadIdx.x;
    if (id >= OUT0) return;
    int q = id % 41; int rest = id / 41;
    int cc = rest % 9; rest /= 9; int r = rest % 9; int b = rest / 9;
    float val;
    if (q == 0) {
        val = ws[WB_OFF + b*81 + r*9 + cc];
    } else if (q <= 8) {
        int o = q - 1;
        const float* p = ws + X3_OFF + ((size_t)(b*9 + r)*9 + cc)*64;
        float s = x2_b[o];
        for (int i = 0; i < 64; ++i) s += p[i]*x2_k[i*8 + o];
        val = LEAKY(s);
    } else {
        val = ws[YBR_OFF + ((size_t)(b*81 + r*9 + cc))*32 + (q - 9)];
    }
    out[id] = val;
}

// ======================= launch =======================
extern "C" void kernel_launch(void* const* d_in, const int* in_sizes, int n_in,
                              void* d_out, int out_size, void* d_ws, size_t ws_size,
                              hipStream_t stream) {
    const float* inp   = (const float*)d_in[0];
    const float* mat   = (const float*)d_in[1];
    const float* w1_k  = (const float*)d_in[2];
    const float* w1_b  = (const float*)d_in[3];
    const float* x1_k  = (const float*)d_in[4];
    const float* x1_b  = (const float*)d_in[5];
    const float* c51_k = (const float*)d_in[6];
    const float* c51_b = (const float*)d_in[7];
    const float* c15_k = (const float*)d_in[8];
    const float* c15_b = (const float*)d_in[9];
    const float* c55_k = (const float*)d_in[10];
    const float* c55_b = (const float*)d_in[11];
    const float* x2_k  = (const float*)d_in[12];
    const float* x2_b  = (const float*)d_in[13];
    const float* y17_k = (const float*)d_in[14];
    const float* y17_b = (const float*)d_in[15];
    const float* y71_k = (const float*)d_in[16];
    const float* y71_b = (const float*)d_in[17];
    const float* yc_k  = (const float*)d_in[18];
    const float* yc_b  = (const float*)d_in[19];
    const float* d1_k  = (const float*)d_in[20];
    const float* d2_k  = (const float*)d_in[21];
    const float* h1_w  = (const float*)d_in[22];
    const float* h1_b  = (const float*)d_in[23];
    const float* h2_w  = (const float*)d_in[24];
    const float* h2_b  = (const float*)d_in[25];
    const float* h3_w  = (const float*)d_in[26];
    const float* h3_b  = (const float*)d_in[27];

    float* ws  = (float*)d_ws;
    float* out = (float*)d_out;
    float* cs  = out + OUT0;

    hipLaunchKernelGGL(prep_kernel, dim3(33), dim3(256), 0, stream,
        inp, mat, w1_k, w1_b, x1_k, x1_b, y17_k, y17_b, y71_k, y71_b,
        yc_k, yc_b, d1_k, d2_k, h1_w, h1_b, h2_w, h2_b, h3_w, h3_b, ws);
    hipLaunchKernelGGL(fista_kernel, dim3(96), dim3(704), 0, stream, ws, cs);
    hipLaunchKernelGGL(c51_kernel, dim3(2592), dim3(256), 0, stream, cs, c51_k, c51_b, ws + X1_OFF);
    hipLaunchKernelGGL(c15_kernel, dim3(1296), dim3(256), 0, stream, ws + X1_OFF, c15_k, c15_b, ws + X2_OFF);
    hipLaunchKernelGGL(c55_kernel, dim3(648), dim3(256), 0, stream, ws + X2_OFF, c55_k, c55_b, ws + X3_OFF);
    hipLaunchKernelGGL(out_kernel, dim3(416), dim3(256), 0, stream, ws, x2_k, x2_b, out);
}